// Round 1
// baseline (86.811 us; speedup 1.0000x reference)
//
#include <hip/hip_runtime.h>

#define N_WIRES 4
#define N_LAYERS 3
#define DIM 16

__device__ __forceinline__ float2 cmul(float2 a, float2 b) {
    return make_float2(a.x * b.x - a.y * b.y, a.x * b.y + a.y * b.x);
}
__device__ __forceinline__ float2 cadd(float2 a, float2 b) {
    return make_float2(a.x + b.x, a.y + b.y);
}

__global__ __launch_bounds__(256) void qenc_kernel(
    const float4* __restrict__ x4, const float* __restrict__ params,
    float4* __restrict__ out4, int B)
{
    // 12 variational Rot matrices, shared by the whole batch.
    // Layout per matrix: re00, im00, re01, im01, re10, im10, re11, im11
    __shared__ __align__(16) float Us[N_LAYERS * N_WIRES][8];
    const int t = threadIdx.x;
    if (t < N_LAYERS * N_WIRES) {
        const float phi = params[t * 3 + 0];
        const float th  = params[t * 3 + 1];
        const float om  = params[t * 3 + 2];
        float c, s, ca, sa, cb, sb;
        __sincosf(0.5f * th, &s, &c);
        __sincosf(0.5f * (phi + om), &sa, &ca);
        __sincosf(0.5f * (phi - om), &sb, &cb);
        // U = RZ(om) @ RY(th) @ RZ(phi):
        // U00 = c e^{-i(phi+om)/2}; U01 = -s e^{ i(phi-om)/2}
        // U10 = s e^{-i(phi-om)/2}; U11 =  c e^{ i(phi+om)/2}
        Us[t][0] =  c * ca;  Us[t][1] = -c * sa;
        Us[t][2] = -s * cb;  Us[t][3] = -s * sb;
        Us[t][4] =  s * cb;  Us[t][5] = -s * sb;
        Us[t][6] =  c * ca;  Us[t][7] =  c * sa;
    }
    __syncthreads();

    const int b = blockIdx.x * blockDim.x + t;
    if (b >= B) return;

    const float4 xv = x4[b];
    const float xa[4] = {xv.x, xv.y, xv.z, xv.w};
    float cx[4], sx[4];
#pragma unroll
    for (int i = 0; i < 4; i++) __sincosf(0.5f * xa[i], &sx[i], &cx[i]);

    // Encoding: per-wire gate chain applied to |0>, giving product state
    // wire i: RY(x[i+3]) RX(x[i+2]) RZ(x[i+1]) RY(x[i]) |0>
    float2 w0[4], w1[4];
#pragma unroll
    for (int i = 0; i < 4; i++) {
        const int i1 = (i + 1) & 3, i2 = (i + 2) & 3, i3 = (i + 3) & 3;
        // RY(x[i]) |0> = (c, s), real
        const float r0 = cx[i], r1 = sx[i];
        // RZ(x[i1]): v0 *= (c - i s); v1 *= (c + i s)   (v real here)
        float2 n0 = make_float2(r0 * cx[i1], -r0 * sx[i1]);
        float2 n1 = make_float2(r1 * cx[i1],  r1 * sx[i1]);
        // RX(x[i2]): [[c, -is], [-is, c]];  -i*(a+bi) = b - ai
        const float c2 = cx[i2], s2 = sx[i2];
        float2 m0 = make_float2(c2 * n0.x + s2 * n1.y,  c2 * n0.y - s2 * n1.x);
        float2 m1 = make_float2(s2 * n0.y + c2 * n1.x, -s2 * n0.x + c2 * n1.y);
        // RY(x[i3]): new0 = c v0 - s v1; new1 = s v0 + c v1
        const float c3 = cx[i3], s3 = sx[i3];
        w0[i] = make_float2(c3 * m0.x - s3 * m1.x, c3 * m0.y - s3 * m1.y);
        w1[i] = make_float2(s3 * m0.x + c3 * m1.x, s3 * m0.y + c3 * m1.y);
    }

    // Tensor product into 16 amplitudes. Wire 0 is the most significant bit:
    // st[((b0*2+b1)*2+b2)*2+b3] = w_{b0}[0] * w_{b1}[1] * w_{b2}[2] * w_{b3}[3]
    float2 p01[4], p23[4];
    p01[0] = cmul(w0[0], w0[1]); p01[1] = cmul(w0[0], w1[1]);
    p01[2] = cmul(w1[0], w0[1]); p01[3] = cmul(w1[0], w1[1]);
    p23[0] = cmul(w0[2], w0[3]); p23[1] = cmul(w0[2], w1[3]);
    p23[2] = cmul(w1[2], w0[3]); p23[3] = cmul(w1[2], w1[3]);
    float2 st[16];
#pragma unroll
    for (int i = 0; i < 4; i++)
#pragma unroll
        for (int j = 0; j < 4; j++)
            st[i * 4 + j] = cmul(p01[i], p23[j]);

    // Variational layers
#pragma unroll
    for (int l = 0; l < N_LAYERS; l++) {
#pragma unroll
        for (int q = 0; q < N_WIRES; q++) {
            const float4* uv = (const float4*)Us[l * 4 + q];
            const float4 ua = uv[0], ub = uv[1];
            const float2 U00 = make_float2(ua.x, ua.y);
            const float2 U01 = make_float2(ua.z, ua.w);
            const float2 U10 = make_float2(ub.x, ub.y);
            const float2 U11 = make_float2(ub.z, ub.w);
            const int m = 8 >> q;
#pragma unroll
            for (int k = 0; k < 16; k++) {
                if (k & m) continue;
                const float2 v0 = st[k], v1 = st[k | m];
                st[k]     = cadd(cmul(U00, v0), cmul(U01, v1));
                st[k | m] = cadd(cmul(U10, v0), cmul(U11, v1));
            }
        }
        // CNOT chain: control c (mask 8>>c), target c+1 (mask 4>>c) —
        // pure register swaps, free after unroll.
#pragma unroll
        for (int c = 0; c < 3; c++) {
            const int cm = 8 >> c, tm = 4 >> c;
#pragma unroll
            for (int k = 0; k < 16; k++) {
                if ((k & cm) && !(k & tm)) {
                    const float2 tmp = st[k];
                    st[k] = st[k | tm];
                    st[k | tm] = tmp;
                }
            }
        }
    }

    // Pauli-Z expectations
    float p[16];
#pragma unroll
    for (int k = 0; k < 16; k++) p[k] = st[k].x * st[k].x + st[k].y * st[k].y;

    float z[4];
#pragma unroll
    for (int q = 0; q < 4; q++) {
        const int m = 8 >> q;
        float acc = 0.f;
#pragma unroll
        for (int k = 0; k < 16; k++) acc += (k & m) ? -p[k] : p[k];
        z[q] = acc;
    }

    out4[b] = make_float4(z[0], z[1], z[2], z[3]);
}

extern "C" void kernel_launch(void* const* d_in, const int* in_sizes, int n_in,
                              void* d_out, int out_size, void* d_ws, size_t ws_size,
                              hipStream_t stream) {
    const float* x      = (const float*)d_in[0];
    const float* params = (const float*)d_in[1];
    float* out          = (float*)d_out;
    const int B = in_sizes[0] / 4;  // x is (B, 4) float32
    const int block = 256;
    const int grid = (B + block - 1) / block;
    qenc_kernel<<<grid, block, 0, stream>>>(
        (const float4*)x, params, (float4*)out, B);
}